// Round 13
// baseline (169.607 us; speedup 1.0000x reference)
//
#include <hip/hip_runtime.h>

typedef __attribute__((ext_vector_type(8))) short  bf16x8;
typedef __attribute__((ext_vector_type(4))) float  f32x4;

#define S_LEN 4096
#define DH    64
#define NEGF  10000.0f

#define NSLOT   288            // sum over qt of ceil((qt+1)/8)
#define PSTRIDE 4224           // per-partial floats: 64 m + 64 l + 4096 o

__device__ __forceinline__ unsigned short f2bf(float f) {
  unsigned u = __float_as_uint(f);
  u += 0x7FFF + ((u >> 16) & 1);          // RNE
  return (unsigned short)(u >> 16);
}

__device__ __forceinline__ bf16x8 pack8(float4 a, float4 b) {
  bf16x8 r;
  r[0] = (short)f2bf(a.x); r[1] = (short)f2bf(a.y);
  r[2] = (short)f2bf(a.z); r[3] = (short)f2bf(a.w);
  r[4] = (short)f2bf(b.x); r[5] = (short)f2bf(b.y);
  r[6] = (short)f2bf(b.z); r[7] = (short)f2bf(b.w);
  return r;
}

// XOR-swizzled byte offset in a [rows][64 bf16] row-major LDS tile (stride 128B)
__device__ __forceinline__ int swz(int row, int colb) {
  return (row << 7) + (colb ^ ((row & 7) << 4));
}

// ---------------------------------------------------------------------------
// Kernel 1: balanced split-KV partials. Block = (b, qt, chunk c of <=8 KV
// tiles). 4 waves x 16 q-rows; R5-verified tile loop; 24KB LDS -> 6 blk/CU.
// Partials (m,l,o) -> ws slot b*288 + blockIdx.x. Degen rows (q<fb,
// reference additive-mask semantics) recomputed by the c==0 blocks.
__global__ __launch_bounds__(256, 1)
void attn_part(const float* __restrict__ Q, const float* __restrict__ K,
               const float* __restrict__ V, const int* __restrict__ Msk,
               float* __restrict__ O, float* __restrict__ ws) {
  __shared__ __align__(16) unsigned char smem[24576];
  __shared__ int sfb;
  unsigned char* smK  = smem;            // [64 k][64 d] bf16 swizzled (8KB)
  unsigned char* smVt = smem + 8192;     // [64 d][64 k] bf16 swizzled (8KB)
  unsigned char* smP  = smem + 16384;    // 4 waves x [16 q][64 k] (8KB)

  const int tid  = threadIdx.x;
  const int lane = tid & 63;
  const int wid  = tid >> 6;
  const int p    = lane & 15;
  const int h    = lane >> 4;

  const int b   = blockIdx.y;
  const int rem = blockIdx.x;            // = base(qt) + c
  int g = 0;
  while (4 * (g + 1) * (g + 2) <= rem) ++g;       // group g: qt in [8g,8g+7]
  const int off = rem - 4 * g * (g + 1);
  const int qt  = 8 * g + off / (g + 1);
  const int c   = off - (off / (g + 1)) * (g + 1);
  const int q0  = qt << 6;

  const float* Qb = Q + ((size_t)b * S_LEN) * DH;
  const float* Kb = K + ((size_t)b * S_LEN) * DH;
  const float* Vb = V + ((size_t)b * S_LEN) * DH;
  const int*   Mb = Msk + b * S_LEN;

  // ---- Q fragments (A operand: row = lane&15; slots = contiguous d) ----
  bf16x8 qf[2];
  {
    const float* qp = Qb + (size_t)(q0 + wid * 16 + p) * DH + h * 8;
    const float4* q4a = (const float4*)(qp);
    const float4* q4b = (const float4*)(qp + 32);
    qf[0] = pack8(q4a[0], q4a[1]);
    qf[1] = pack8(q4b[0], q4b[1]);
  }

  f32x4 o[4];
  float m_r[4], l_r[4];
#pragma unroll
  for (int j = 0; j < 4; ++j)
#pragma unroll
    for (int e = 0; e < 4; ++e) o[j][e] = 0.f;
#pragma unroll
  for (int rr = 0; rr < 4; ++rr) { m_r[rr] = -INFINITY; l_r[rr] = 0.f; }

  const int qrb = q0 + wid * 16 + h * 4;

  const int j0 = c << 3;
  const int j1 = min(j0 + 8, qt + 1);
  for (int j = j0; j < j1; ++j) {
    const int kv0 = j << 6;
    __syncthreads();                     // prior tile consumed

    // ---- stage K (swizzled) and V^T (swizzled) — R5-verified ----
#pragma unroll
    for (int cc = 0; cc < 2; ++cc) {
      const int chunk = tid + (cc << 8);
      const int row   = chunk >> 3;
      const int colf  = (chunk & 7) << 3;
      const float4* kp = (const float4*)(Kb + (size_t)(kv0 + row) * DH + colf);
      float4 k0 = kp[0], k1 = kp[1];
      *(bf16x8*)(smK + swz(row, colf << 1)) = pack8(k0, k1);

      const int dcol = tid & 63;
      const int kc   = (tid >> 6) + (cc << 2);
      bf16x8 vp;
#pragma unroll
      for (int e = 0; e < 8; ++e)
        vp[e] = (short)f2bf(Vb[(size_t)(kv0 + kc * 8 + e) * DH + dcol]);
      *(bf16x8*)(smVt + swz(dcol, kc << 4)) = vp;
    }
    __syncthreads();

    // ---- QK^T ----
    f32x4 acc[4];
#pragma unroll
    for (int t16 = 0; t16 < 4; ++t16) {
      f32x4 a;
#pragma unroll
      for (int e = 0; e < 4; ++e) a[e] = 0.f;
#pragma unroll
      for (int cc = 0; cc < 2; ++cc) {
        bf16x8 kb = *(const bf16x8*)(smK + swz(t16 * 16 + p, cc * 64 + h * 16));
        a = __builtin_amdgcn_mfma_f32_16x16x32_bf16(qf[cc], kb, a, 0, 0, 0);
      }
      acc[t16] = a;
    }

    // ---- masks + scores ----
    float pen[4];
#pragma unroll
    for (int t16 = 0; t16 < 4; ++t16)
      pen[t16] = Mb[kv0 + t16 * 16 + p] ? 0.f : -NEGF;

    float sc[4][4];
#pragma unroll
    for (int t16 = 0; t16 < 4; ++t16) {
      const int key = kv0 + t16 * 16 + p;
#pragma unroll
      for (int rr = 0; rr < 4; ++rr) {
        float v = fmaf(acc[t16][rr], 0.125f, pen[t16]);
        if (key > qrb + rr) v -= NEGF;   // causal
        sc[t16][rr] = v;
      }
    }

    // ---- online softmax (chunk-local partial) ----
    float alpha[4];
#pragma unroll
    for (int rr = 0; rr < 4; ++rr) {
      float v = fmaxf(fmaxf(sc[0][rr], sc[1][rr]), fmaxf(sc[2][rr], sc[3][rr]));
      v = fmaxf(v, __shfl_xor(v, 1));
      v = fmaxf(v, __shfl_xor(v, 2));
      v = fmaxf(v, __shfl_xor(v, 4));
      v = fmaxf(v, __shfl_xor(v, 8));
      const float mn = fmaxf(m_r[rr], v);
      alpha[rr] = __expf(m_r[rr] - mn);
      m_r[rr] = mn;
    }

    unsigned char* Pw = smP + (wid << 11);
    float rs[4] = {0.f, 0.f, 0.f, 0.f};
#pragma unroll
    for (int t16 = 0; t16 < 4; ++t16) {
#pragma unroll
      for (int rr = 0; rr < 4; ++rr) {
        float pv = __expf(sc[t16][rr] - m_r[rr]);
        rs[rr] += pv;
        *(unsigned short*)(Pw + swz(h * 4 + rr, (t16 * 16 + p) << 1)) = f2bf(pv);
      }
    }
#pragma unroll
    for (int rr = 0; rr < 4; ++rr) {
      float v = rs[rr];
      v += __shfl_xor(v, 1);
      v += __shfl_xor(v, 2);
      v += __shfl_xor(v, 4);
      v += __shfl_xor(v, 8);
      l_r[rr] = l_r[rr] * alpha[rr] + v;
    }
#pragma unroll
    for (int jj = 0; jj < 4; ++jj)
#pragma unroll
      for (int rr = 0; rr < 4; ++rr) o[jj][rr] *= alpha[rr];

    // same-wave P write -> read: drain LDS, keep reads below (rule #18)
    asm volatile("s_waitcnt lgkmcnt(0)" ::: "memory");
    __builtin_amdgcn_sched_barrier(0);

    // ---- PV ----
    bf16x8 pf[2];
#pragma unroll
    for (int cc = 0; cc < 2; ++cc)
      pf[cc] = *(const bf16x8*)(Pw + swz(p, cc * 64 + h * 16));
#pragma unroll
    for (int jj = 0; jj < 4; ++jj)
#pragma unroll
      for (int cc = 0; cc < 2; ++cc) {
        bf16x8 vb = *(const bf16x8*)(smVt + swz(jj * 16 + p, cc * 64 + h * 16));
        o[jj] = __builtin_amdgcn_mfma_f32_16x16x32_bf16(pf[cc], vb, o[jj], 0, 0, 0);
      }
  }

  // ---- write partial (m, l, o) to ws slot ----
  {
    float* W = ws + (size_t)(b * NSLOT + rem) * PSTRIDE;
#pragma unroll
    for (int rr = 0; rr < 4; ++rr) {
      const int ql = wid * 16 + h * 4 + rr;
      if (p == 0) { W[ql] = m_r[rr]; W[64 + ql] = l_r[rr]; }
#pragma unroll
      for (int jj = 0; jj < 4; ++jj)
        W[128 + ql * 64 + jj * 16 + p] = o[jj][rr];
    }
  }

  // ---- degenerate rows (c==0 blocks only): q === qt (mod 64), q < fb ----
  if (c == 0) {
    if (tid == 0) sfb = S_LEN;
    __syncthreads();
    {
      int loc = S_LEN;
      for (int k = tid; k < S_LEN; k += 256)
        if (Mb[k]) { loc = k; break; }
      if (loc < S_LEN) atomicMin(&sfb, loc);
    }
    __syncthreads();
    const int fb = sfb;

    for (int dq = qt; dq < fb; dq += 64) {
      __syncthreads();
      float* ssc   = (float*)smem;         // [4096]
      float* sq    = (float*)smem + 4096;  // [64]
      float* sred  = (float*)smem + 4160;  // [8]
      float* spart = (float*)smem + 4224;  // [4][64]
      if (tid < 64) sq[tid] = Qb[(size_t)dq * DH + tid];
      __syncthreads();

      float lmax = -1e30f;
      for (int k = tid; k < S_LEN; k += 256) {
        float s = -1e30f;
        if (k <= dq || Mb[k]) {
          const float4* kp = (const float4*)(Kb + (size_t)k * DH);
          float acc2 = 0.f;
#pragma unroll
          for (int d4 = 0; d4 < 16; ++d4) {
            const float4 kv = kp[d4];
            acc2 += sq[d4 * 4 + 0] * kv.x + sq[d4 * 4 + 1] * kv.y +
                    sq[d4 * 4 + 2] * kv.z + sq[d4 * 4 + 3] * kv.w;
          }
          s = acc2 * 0.125f;
        }
        ssc[k] = s;
        lmax = fmaxf(lmax, s);
      }
#pragma unroll
      for (int o2 = 32; o2; o2 >>= 1) lmax = fmaxf(lmax, __shfl_xor(lmax, o2));
      if (lane == 0) sred[wid] = lmax;
      __syncthreads();
      const float gmax = fmaxf(fmaxf(sred[0], sred[1]), fmaxf(sred[2], sred[3]));

      float lsum = 0.f;
      for (int k = tid; k < S_LEN; k += 256) {
        const float e = (ssc[k] > -1e29f) ? __expf(ssc[k] - gmax) : 0.f;
        ssc[k] = e;
        lsum += e;
      }
#pragma unroll
      for (int o2 = 32; o2; o2 >>= 1) lsum += __shfl_xor(lsum, o2);
      if (lane == 0) sred[4 + wid] = lsum;
      __syncthreads();
      const float inv = 1.f / (sred[4] + sred[5] + sred[6] + sred[7]);

      {
        const int k0d = wid << 10;          // wave owns 1024 keys
        float a0 = 0.f, a1 = 0.f;
        for (int kk = 0; kk < 1024; kk += 2) {
          a0 = fmaf(ssc[k0d + kk + 0], Vb[(size_t)(k0d + kk + 0) * DH + lane], a0);
          a1 = fmaf(ssc[k0d + kk + 1], Vb[(size_t)(k0d + kk + 1) * DH + lane], a1);
        }
        spart[wid * 64 + lane] = a0 + a1;
      }
      __syncthreads();
      if (tid < 64) {
        const float num = spart[tid] + spart[64 + tid] + spart[128 + tid] +
                          spart[192 + tid];
        O[((size_t)b * S_LEN + dq) * DH + tid] = num * inv;
      }
    }
  }
}

// ---------------------------------------------------------------------------
// Kernel 2: merge <=8 chunk-partials per (b, qt); skip degen rows (q < fb).
__global__ __launch_bounds__(256, 1)
void attn_merge(const int* __restrict__ Msk, const float* __restrict__ ws,
                float* __restrict__ O) {
  __shared__ int sfb;
  const int tid = threadIdx.x;
  const int qt = blockIdx.x, b = blockIdx.y;
  const int g = qt >> 3;
  const int base = (g + 1) * (qt - 4 * g);
  const int Nc = g + 1;
  const int*   Mb = Msk + b * S_LEN;

  if (tid == 0) sfb = S_LEN;
  __syncthreads();
  {
    int loc = S_LEN;
    for (int k = tid; k < S_LEN; k += 256)
      if (Mb[k]) { loc = k; break; }
    if (loc < S_LEN) atomicMin(&sfb, loc);
  }
  __syncthreads();
  const int fb = sfb;

  const int ql = tid >> 2;               // q row 0..63
  const int cg = tid & 3;                // col group (16 cols)
  const int q  = (qt << 6) + ql;
  if (q < fb) return;                    // degen: written by attn_part

  const float* P0 = ws + (size_t)(b * NSLOT + base) * PSTRIDE;

  float M = -INFINITY;
  for (int cc = 0; cc < Nc; ++cc) M = fmaxf(M, P0[(size_t)cc * PSTRIDE + ql]);
  float w[8];
  float L = 0.f;
  for (int cc = 0; cc < Nc; ++cc) {
    w[cc] = __expf(P0[(size_t)cc * PSTRIDE + ql] - M);
    L += P0[(size_t)cc * PSTRIDE + 64 + ql] * w[cc];
  }
  const float inv = 1.f / L;

  float* Ob = O + ((size_t)b * S_LEN + q) * DH;
#pragma unroll 4
  for (int e = 0; e < 16; ++e) {
    const int col = cg * 16 + e;
    float num = 0.f;
    for (int cc = 0; cc < Nc; ++cc)
      num += P0[(size_t)cc * PSTRIDE + 128 + ql * 64 + col] * w[cc];
    Ob[col] = num * inv;
  }
}

extern "C" void kernel_launch(void* const* d_in, const int* in_sizes, int n_in,
                              void* d_out, int out_size, void* d_ws, size_t ws_size,
                              hipStream_t stream) {
  const float* Q = (const float*)d_in[0];
  const float* K = (const float*)d_in[1];
  const float* V = (const float*)d_in[2];
  const int*   M = (const int*)d_in[3];
  float* O = (float*)d_out;
  float* ws = (float*)d_ws;
  // needed: 4 batches * 288 slots * 4224 floats * 4B = 19.46 MB
  const size_t need = (size_t)4 * NSLOT * PSTRIDE * sizeof(float);
  if (ws_size >= need) {
    attn_part<<<dim3(NSLOT, 4), dim3(256), 0, stream>>>(Q, K, V, M, O, ws);
    attn_merge<<<dim3(64, 4), dim3(256), 0, stream>>>(M, ws, O);
  } else {
    // fallback: should not happen; re-run partials per chunk writing directly
    // is not possible without ws, so do the whole thing with chunk = full row
    // range via attn_part semantics degraded to a single chunk. Instead we
    // simply serialize: launch attn_part with ws==nullptr is invalid, so use
    // a minimal-correctness path: one block per (b,qt) covering all tiles.
    // (288-slot layout with c==0 only; merge trivial.) Reuse attn_part by
    // noting qt-chunk c always valid; with insufficient ws we cannot run.
    // Pragmatically: run with whatever ws there is only if it fits one batch
    // at a time is impossible in-graph -> fall back to attn_part+merge anyway.
    attn_part<<<dim3(NSLOT, 4), dim3(256), 0, stream>>>(Q, K, V, M, O, ws);
    attn_merge<<<dim3(64, 4), dim3(256), 0, stream>>>(M, ws, O);
  }
}